// Round 17
// baseline (71.462 us; speedup 1.0000x reference)
//
#include <hip/hip_runtime.h>

#define NQ   65536
#define NC   4096
#define SOUT 64
#define NR   4                 // monomials (DEGREE=1, NDIM=3)
#define KTOT (NC + 64)         // 4160: k padded (chunk 64 = poly frags)
#define BM   32                // 32 q-rows per block; 4 waves k-split 4-ways
#define NCH  (NC / 64)         // 64 r2 chunks of BK=64

typedef float    f32x4 __attribute__((ext_vector_type(4)));
typedef _Float16 f16x8 __attribute__((ext_vector_type(8)));
typedef __fp16   h16x2 __attribute__((ext_vector_type(2)));
typedef unsigned uint4v __attribute__((ext_vector_type(4)));

// ---------------- pre-kernels (write d_ws; deterministic every call) ---------

// Fragment-contiguous packed B: bpack[((ch*4+nf)*2+kk)*512 + l*8]; lane l holds
// 8 f16 {coeffs[k][n]}, n=nf*16+(l&15), k=ch*64+kk*32+(l>>4)*8..+7.
// TPS constant 0.5*ln2 folded into kernel coeffs; poly unscaled; zeros after.
__global__ void prep_bpack(const float* __restrict__ coeffs, _Float16* __restrict__ bp) {
    const int idx = blockIdx.x * 256 + threadIdx.x;
    if (idx >= 65 * 4 * 2 * 64) return;
    const int l  = idx & 63;
    const int kk = (idx >> 6) & 1;
    const int nf = (idx >> 7) & 3;
    const int ch = idx >> 9;
    const int n  = nf * 16 + (l & 15);
    const int ks = ch * 64 + kk * 32 + (l >> 4) * 8;
    f16x8 v;
    #pragma unroll
    for (int j = 0; j < 8; ++j) {
        const int k = ks + j;
        float f = 0.0f;
        if (k < NC)           f = coeffs[(size_t)k * SOUT + n] * 0.34657359f;
        else if (k < NC + NR) f = coeffs[(size_t)k * SOUT + n];
        v[j] = (_Float16)f;
    }
    *(f16x8*)(bp + (size_t)idx * 8) = v;
}

// Ye[k] = [-2y0, -2y1, -2y2, 1, |y|^2 + 0.02, 0,0,0] for k < NC; zeros padded.
// +0.02 keeps the MFMA-computed r2 strictly positive against f16 input noise,
// removing the per-eval clamp (round 16, verified absmax 4.0).
__global__ void prep_ye(const float* __restrict__ y, _Float16* __restrict__ ye) {
    const int k = blockIdx.x * 256 + threadIdx.x;
    if (k >= KTOT) return;
    f16x8 r = {};
    if (k < NC) {
        const float a = y[k * 3 + 0], b = y[k * 3 + 1], c = y[k * 3 + 2];
        r[0] = (_Float16)(-2.0f * a); r[1] = (_Float16)(-2.0f * b);
        r[2] = (_Float16)(-2.0f * c); r[3] = (_Float16)1.0f;
        r[4] = (_Float16)(a * a + b * b + c * c + 0.02f);
    }
    *(f16x8*)(ye + (size_t)k * 8) = r;
}

// ---------------- main kernel ------------------------------------------------
// Round-16 body + 4-way K-split: block = 4 waves sharing the same 32 q-rows;
// wave kh handles k-chunks [kh*16, kh*16+16). Grid 2048, LDS 24 KB -> 6
// blocks/CU -> 24 waves/CU TLP, same chip-wide instruction totals.
// launch_bounds(256,4): RA cap 128 regs (body needs ~88 incl. acc) -> NO
// spills (round 13's (256,6) cap of ~85 caused the spill regression).
// Partials: waves 1..3 write [elem][lane] LDS (conflict-free), wave 0 merges.
__launch_bounds__(256, 4)
__global__ void rbf_mfma15(const float* __restrict__ x,
                           const _Float16* __restrict__ ye,
                           const float* __restrict__ shift,
                           const float* __restrict__ scale,
                           const _Float16* __restrict__ bp,
                           float* __restrict__ out) {
    __shared__ float red[3][32 * 64];   // 24 KB: [src wave-1][elem][lane]

    const int t    = threadIdx.x;
    const int kh   = t >> 6;            // wave = k-quarter
    const int lane = t & 63;
    const int l15  = lane & 15;
    const int lg   = lane >> 4;
    const int qb   = blockIdx.x * BM;   // all waves share these 32 q-rows
    const int s    = kh * 16;           // first chunk of this k-quarter

    // Xe B-fragments per q-half: lg==0 lanes hold [x0,x1,x2,xsq,1,0,0,0]
    f16x8 xef[2];
    uint2  poly01[2];
    #pragma unroll
    for (int qh = 0; qh < 2; ++qh) {
        const int q = qb + qh * 16 + l15;
        const float a = x[q * 3 + 0], b = x[q * 3 + 1], c = x[q * 3 + 2];
        f16x8 v = {};
        if (lg == 0) {
            v[0] = (_Float16)a; v[1] = (_Float16)b; v[2] = (_Float16)c;
            v[3] = (_Float16)(a * a + b * b + c * c); v[4] = (_Float16)1.0f;
        }
        xef[qh] = v;
        h16x2 p0 = __builtin_amdgcn_cvt_pkrtz(1.0f, (a - shift[0]) / scale[0]);
        h16x2 p1 = __builtin_amdgcn_cvt_pkrtz((b - shift[1]) / scale[1],
                                              (c - shift[2]) / scale[2]);
        poly01[qh].x = __builtin_bit_cast(unsigned, p0);
        poly01[qh].y = __builtin_bit_cast(unsigned, p1);
    }

    // per-lane bases
    const _Float16* yeb = ye + ((size_t)((l15 >> 2) * 8 + (l15 & 3))) * 8;  // perm rows
    const _Float16* bpl = bp + (size_t)lane * 8;                            // packed frags

    f32x4 acc[2][4] = {};   // [qh][nf]

    for (int ch = s; ch < s + 16; ++ch) {
        // ---- Y rows (head of the r2 chain; issue first) ----
        f16x8 Y[4];
        #pragma unroll
        for (int kt = 0; kt < 4; ++kt)
            Y[kt] = *(const f16x8*)(yeb + ch * 512 + (kt & 1) * 256 + (kt >> 1) * 32);

        // ---- B fragments: coalesced 1 KB bursts ----
        f16x8 B[4][2];
        #pragma unroll
        for (int nf = 0; nf < 4; ++nf)
            #pragma unroll
            for (int kk = 0; kk < 2; ++kk)
                B[nf][kk] = *(const f16x8*)(bpl + ((size_t)((ch * 4 + nf) * 2 + kk) << 9));

        // ---- per q-half: r2 tiles + f-eval + out-GEMM ----
        #pragma unroll
        for (int qh = 0; qh < 2; ++qh) {
            uint2 w[4];
            #pragma unroll
            for (int kt = 0; kt < 4; ++kt) {
                f32x4 z = {};
                const f32x4 r2 = __builtin_amdgcn_mfma_f32_16x16x32_f16(
                    Y[kt], xef[qh], z, 0, 0, 0);
                float f[4];
                #pragma unroll
                for (int r = 0; r < 4; ++r) {
                    // r2 > 0 by ysq bias; |.| folds into v_log as input modifier
                    f[r] = r2[r] * __log2f(__builtin_fabsf(r2[r]));
                }
                h16x2 h0 = __builtin_amdgcn_cvt_pkrtz(f[0], f[1]);
                h16x2 h1 = __builtin_amdgcn_cvt_pkrtz(f[2], f[3]);
                w[kt].x = __builtin_bit_cast(unsigned, h0);
                w[kt].y = __builtin_bit_cast(unsigned, h1);
            }
            const uint4v a0 = {w[0].x, w[0].y, w[2].x, w[2].y};
            const uint4v a1 = {w[1].x, w[1].y, w[3].x, w[3].y};
            const f16x8 af0 = __builtin_bit_cast(f16x8, a0);
            const f16x8 af1 = __builtin_bit_cast(f16x8, a1);
            #pragma unroll
            for (int nf = 0; nf < 4; ++nf) {
                acc[qh][nf] = __builtin_amdgcn_mfma_f32_16x16x32_f16(
                    af0, B[nf][0], acc[qh][nf], 0, 0, 0);
                acc[qh][nf] = __builtin_amdgcn_mfma_f32_16x16x32_f16(
                    af1, B[nf][1], acc[qh][nf], 0, 0, 0);
            }
        }
    }

    if (kh == 3) {
        // ---- poly tail: chunk 64, kk=0 frags; A = [1,xh0,xh1,xh2,0...] ----
        #pragma unroll
        for (int qh = 0; qh < 2; ++qh) {
            uint4v ap = {};
            if (lg == 0) { ap.x = poly01[qh].x; ap.y = poly01[qh].y; }
            const f16x8 afp = __builtin_bit_cast(f16x8, ap);
            #pragma unroll
            for (int nf = 0; nf < 4; ++nf) {
                const f16x8 bpf = *(const f16x8*)(
                    bpl + ((size_t)((NCH * 4 + nf) * 2) << 9));
                acc[qh][nf] = __builtin_amdgcn_mfma_f32_16x16x32_f16(
                    afp, bpf, acc[qh][nf], 0, 0, 0);
            }
        }
    }

    if (kh != 0) {
        // write partials: [elem][lane] layout -> conflict-free b32 stores
        #pragma unroll
        for (int qh = 0; qh < 2; ++qh)
            #pragma unroll
            for (int nf = 0; nf < 4; ++nf)
                #pragma unroll
                for (int r = 0; r < 4; ++r)
                    red[kh - 1][(qh * 16 + nf * 4 + r) * 64 + lane] = acc[qh][nf][r];
    }
    __syncthreads();
    if (kh == 0) {
        #pragma unroll
        for (int qh = 0; qh < 2; ++qh)
            #pragma unroll
            for (int nf = 0; nf < 4; ++nf)
                #pragma unroll
                for (int r = 0; r < 4; ++r) {
                    const int e = (qh * 16 + nf * 4 + r) * 64 + lane;
                    acc[qh][nf][r] += (red[0][e] + red[1][e]) + red[2][e];
                }

        // epilogue: C/D col=lane&15 (n), row=lg*4+r (q)
        #pragma unroll
        for (int qh = 0; qh < 2; ++qh)
            #pragma unroll
            for (int nf = 0; nf < 4; ++nf)
                #pragma unroll
                for (int r = 0; r < 4; ++r)
                    out[(size_t)(qb + qh * 16 + lg * 4 + r) * SOUT + nf * 16 + l15] =
                        acc[qh][nf][r];
    }
}

// ---------------- fallback (round-1 kernel) if d_ws too small ----------------
__launch_bounds__(256)
__global__ void rbf_tps_fallback(const float* __restrict__ x,
                                 const float* __restrict__ y,
                                 const float* __restrict__ coeffs,
                                 const float* __restrict__ shift,
                                 const float* __restrict__ scale,
                                 float* __restrict__ out) {
    __shared__ float4 ytile[NC];
    const int tid = threadIdx.x;
    for (int j = tid; j < NC; j += 256) {
        const float a = y[j * 3], b = y[j * 3 + 1], c = y[j * 3 + 2];
        ytile[j] = make_float4(a, b, c, a * a + b * b + c * c);
    }
    __syncthreads();
    const int q = blockIdx.x * 256 + tid;
    const float x0 = x[q * 3], x1 = x[q * 3 + 1], x2 = x[q * 3 + 2];
    const float xsq = x0 * x0 + x1 * x1 + x2 * x2;
    const float xh0 = (x0 - shift[0]) / scale[0];
    const float xh1 = (x1 - shift[1]) / scale[1];
    const float xh2 = (x2 - shift[2]) / scale[2];
    float acc[SOUT];
    {
        const float* c0 = &coeffs[(size_t)(NC + 0) * SOUT];
        const float* c1 = &coeffs[(size_t)(NC + 1) * SOUT];
        const float* c2 = &coeffs[(size_t)(NC + 2) * SOUT];
        const float* c3 = &coeffs[(size_t)(NC + 3) * SOUT];
        #pragma unroll
        for (int s = 0; s < SOUT; ++s)
            acc[s] = c0[s] + xh0 * c1[s] + xh1 * c2[s] + xh2 * c3[s];
    }
    #pragma unroll 2
    for (int j = 0; j < NC; ++j) {
        const float4 yj = ytile[j];
        const float dot = x0 * yj.x + x1 * yj.y + x2 * yj.z;
        float r2 = fmaf(-2.0f, dot, xsq + yj.w);
        r2 = fmaxf(r2, 0.0f);
        const float f = 0.5f * r2 * __logf(fmaxf(r2, 1e-37f));
        const float* __restrict__ cj = &coeffs[(size_t)j * SOUT];
        #pragma unroll
        for (int s = 0; s < SOUT; ++s) acc[s] = fmaf(f, cj[s], acc[s]);
    }
    float4* o4 = (float4*)&out[(size_t)q * SOUT];
    #pragma unroll
    for (int s = 0; s < SOUT / 4; ++s)
        o4[s] = make_float4(acc[4 * s], acc[4 * s + 1], acc[4 * s + 2], acc[4 * s + 3]);
}

extern "C" void kernel_launch(void* const* d_in, const int* in_sizes, int n_in,
                              void* d_out, int out_size, void* d_ws, size_t ws_size,
                              hipStream_t stream) {
    const float* x      = (const float*)d_in[0];
    const float* y      = (const float*)d_in[1];
    const float* coeffs = (const float*)d_in[2];
    const float* shift  = (const float*)d_in[3];
    const float* scale  = (const float*)d_in[4];
    float* out = (float*)d_out;

    const size_t bp_bytes = (size_t)65 * 4 * 2 * 64 * 8 * sizeof(_Float16); // 532,480
    const size_t ye_bytes = (size_t)KTOT * 8 * sizeof(_Float16);            //  66,560

    if (ws_size >= bp_bytes + ye_bytes) {
        _Float16* bpw = (_Float16*)d_ws;
        _Float16* yep = (_Float16*)((char*)d_ws + bp_bytes);
        hipLaunchKernelGGL(prep_bpack, dim3((65 * 4 * 2 * 64 + 255) / 256), dim3(256),
                           0, stream, coeffs, bpw);
        hipLaunchKernelGGL(prep_ye, dim3((KTOT + 255) / 256), dim3(256),
                           0, stream, y, yep);
        hipLaunchKernelGGL(rbf_mfma15, dim3(NQ / BM), dim3(256), 0, stream,
                           x, yep, shift, scale, bpw, out);
    } else {
        hipLaunchKernelGGL(rbf_tps_fallback, dim3(NQ / 256), dim3(256),
                           0, stream, x, y, coeffs, shift, scale, out);
    }
}

// Round 18
// 69.808 us; speedup vs baseline: 1.0237x; 1.0237x over previous
//
#include <hip/hip_runtime.h>

#define NQ   65536
#define NC   4096
#define SOUT 64
#define NR   4                 // monomials (DEGREE=1, NDIM=3)
#define KTOT (NC + 64)         // 4160: k padded (chunk 64 = poly frags)
#define BM   128               // 2 q-groups x 64 q-rows; 2-way K-split
#define NCH  (NC / 64)         // 64 r2 chunks of BK=64

typedef float    f32x4 __attribute__((ext_vector_type(4)));
typedef _Float16 f16x8 __attribute__((ext_vector_type(8)));
typedef __fp16   h16x2 __attribute__((ext_vector_type(2)));
typedef unsigned uint4v __attribute__((ext_vector_type(4)));

// ---------------- pre-kernels (write d_ws; deterministic every call) ---------

// Fragment-contiguous packed B: bpack[((ch*4+nf)*2+kk)*512 + l*8]; lane l holds
// 8 f16 {coeffs[k][n]}, n=nf*16+(l&15), k=ch*64+kk*32+(l>>4)*8..+7.
// TPS constant 0.5*ln2 folded into kernel coeffs; poly unscaled; zeros after.
__global__ void prep_bpack(const float* __restrict__ coeffs, _Float16* __restrict__ bp) {
    const int idx = blockIdx.x * 256 + threadIdx.x;
    if (idx >= 65 * 4 * 2 * 64) return;
    const int l  = idx & 63;
    const int kk = (idx >> 6) & 1;
    const int nf = (idx >> 7) & 3;
    const int ch = idx >> 9;
    const int n  = nf * 16 + (l & 15);
    const int ks = ch * 64 + kk * 32 + (l >> 4) * 8;
    f16x8 v;
    #pragma unroll
    for (int j = 0; j < 8; ++j) {
        const int k = ks + j;
        float f = 0.0f;
        if (k < NC)           f = coeffs[(size_t)k * SOUT + n] * 0.34657359f;
        else if (k < NC + NR) f = coeffs[(size_t)k * SOUT + n];
        v[j] = (_Float16)f;
    }
    *(f16x8*)(bp + (size_t)idx * 8) = v;
}

// Ye[k] = [-2y0, -2y1, -2y2, 1, |y|^2 + 0.02, 0,0,0] for k < NC; zeros padded.
// +0.02 keeps the MFMA-computed r2 strictly positive against f16 input noise,
// removing the per-eval clamp (round 16, verified absmax 4.0).
__global__ void prep_ye(const float* __restrict__ y, _Float16* __restrict__ ye) {
    const int k = blockIdx.x * 256 + threadIdx.x;
    if (k >= KTOT) return;
    f16x8 r = {};
    if (k < NC) {
        const float a = y[k * 3 + 0], b = y[k * 3 + 1], c = y[k * 3 + 2];
        r[0] = (_Float16)(-2.0f * a); r[1] = (_Float16)(-2.0f * b);
        r[2] = (_Float16)(-2.0f * c); r[3] = (_Float16)1.0f;
        r[4] = (_Float16)(a * a + b * b + c * c + 0.02f);
    }
    *(f16x8*)(ye + (size_t)k * 8) = r;
}

// ---------------- main kernel ------------------------------------------------
// Round-16 body, widened to 4 q-halves per wave: block = 4 waves, wave
// (qg=w&1, kh=w>>1) owns 64 q-rows (qh=0..3) and k-chunks [kh*32, kh*32+32).
// The 12 Y/B loads per chunk now serve 4 qh (chip-wide load instrs halved vs
// round 16) and the 4 qh give 4 independent MFMA->log->MFMA chains per chunk
// (in-wave ILP; rounds 13/17 showed TLP doesn't move this kernel).
// No launch_bounds min-waves (spill lessons, rounds 11/13): VGPR ~160 OK.
__launch_bounds__(256)
__global__ void rbf_mfma16(const float* __restrict__ x,
                           const _Float16* __restrict__ ye,
                           const float* __restrict__ shift,
                           const float* __restrict__ scale,
                           const _Float16* __restrict__ bp,
                           float* __restrict__ out) {
    __shared__ float red[2][64 * 64];   // 32 KB: [qg][elem][lane]

    const int t    = threadIdx.x;
    const int wave = t >> 6;
    const int lane = t & 63;
    const int l15  = lane & 15;
    const int lg   = lane >> 4;
    const int qg   = wave & 1;
    const int kh   = wave >> 1;
    const int qb   = blockIdx.x * BM + qg * 64;   // this wave's 64 q-rows
    const int s    = kh * 32;                     // first chunk of this k-half

    // Xe B-fragments per q-half: lg==0 lanes hold [x0,x1,x2,xsq,1,0,0,0]
    f16x8 xef[4];
    uint2  poly01[4];
    #pragma unroll
    for (int qh = 0; qh < 4; ++qh) {
        const int q = qb + qh * 16 + l15;
        const float a = x[q * 3 + 0], b = x[q * 3 + 1], c = x[q * 3 + 2];
        f16x8 v = {};
        if (lg == 0) {
            v[0] = (_Float16)a; v[1] = (_Float16)b; v[2] = (_Float16)c;
            v[3] = (_Float16)(a * a + b * b + c * c); v[4] = (_Float16)1.0f;
        }
        xef[qh] = v;
        h16x2 p0 = __builtin_amdgcn_cvt_pkrtz(1.0f, (a - shift[0]) / scale[0]);
        h16x2 p1 = __builtin_amdgcn_cvt_pkrtz((b - shift[1]) / scale[1],
                                              (c - shift[2]) / scale[2]);
        poly01[qh].x = __builtin_bit_cast(unsigned, p0);
        poly01[qh].y = __builtin_bit_cast(unsigned, p1);
    }

    // per-lane bases
    const _Float16* yeb = ye + ((size_t)((l15 >> 2) * 8 + (l15 & 3))) * 8;  // perm rows
    const _Float16* bpl = bp + (size_t)lane * 8;                            // packed frags

    f32x4 acc[4][4] = {};   // [qh][nf]

    for (int ch = s; ch < s + 32; ++ch) {
        // ---- Y rows (head of the r2 chain; issue first) ----
        f16x8 Y[4];
        #pragma unroll
        for (int kt = 0; kt < 4; ++kt)
            Y[kt] = *(const f16x8*)(yeb + ch * 512 + (kt & 1) * 256 + (kt >> 1) * 32);

        // ---- B fragments: coalesced 1 KB bursts, serve all 4 qh ----
        f16x8 B[4][2];
        #pragma unroll
        for (int nf = 0; nf < 4; ++nf)
            #pragma unroll
            for (int kk = 0; kk < 2; ++kk)
                B[nf][kk] = *(const f16x8*)(bpl + ((size_t)((ch * 4 + nf) * 2 + kk) << 9));

        // ---- per q-half: r2 tiles + f-eval + out-GEMM (4 independent chains) ----
        #pragma unroll
        for (int qh = 0; qh < 4; ++qh) {
            uint2 w[4];
            #pragma unroll
            for (int kt = 0; kt < 4; ++kt) {
                f32x4 z = {};
                const f32x4 r2 = __builtin_amdgcn_mfma_f32_16x16x32_f16(
                    Y[kt], xef[qh], z, 0, 0, 0);
                float f[4];
                #pragma unroll
                for (int r = 0; r < 4; ++r) {
                    // r2 > 0 by ysq bias; |.| folds into v_log as input modifier
                    f[r] = r2[r] * __log2f(__builtin_fabsf(r2[r]));
                }
                h16x2 h0 = __builtin_amdgcn_cvt_pkrtz(f[0], f[1]);
                h16x2 h1 = __builtin_amdgcn_cvt_pkrtz(f[2], f[3]);
                w[kt].x = __builtin_bit_cast(unsigned, h0);
                w[kt].y = __builtin_bit_cast(unsigned, h1);
            }
            const uint4v a0 = {w[0].x, w[0].y, w[2].x, w[2].y};
            const uint4v a1 = {w[1].x, w[1].y, w[3].x, w[3].y};
            const f16x8 af0 = __builtin_bit_cast(f16x8, a0);
            const f16x8 af1 = __builtin_bit_cast(f16x8, a1);
            #pragma unroll
            for (int nf = 0; nf < 4; ++nf) {
                acc[qh][nf] = __builtin_amdgcn_mfma_f32_16x16x32_f16(
                    af0, B[nf][0], acc[qh][nf], 0, 0, 0);
                acc[qh][nf] = __builtin_amdgcn_mfma_f32_16x16x32_f16(
                    af1, B[nf][1], acc[qh][nf], 0, 0, 0);
            }
        }
    }

    if (kh == 1) {
        // ---- poly tail: chunk 64, kk=0 frags; A = [1,xh0,xh1,xh2,0...] ----
        #pragma unroll
        for (int qh = 0; qh < 4; ++qh) {
            uint4v ap = {};
            if (lg == 0) { ap.x = poly01[qh].x; ap.y = poly01[qh].y; }
            const f16x8 afp = __builtin_bit_cast(f16x8, ap);
            #pragma unroll
            for (int nf = 0; nf < 4; ++nf) {
                const f16x8 bpf = *(const f16x8*)(
                    bpl + ((size_t)((NCH * 4 + nf) * 2) << 9));
                acc[qh][nf] = __builtin_amdgcn_mfma_f32_16x16x32_f16(
                    afp, bpf, acc[qh][nf], 0, 0, 0);
            }
        }
        // write partials: [elem][lane] layout -> conflict-free b32 stores
        #pragma unroll
        for (int qh = 0; qh < 4; ++qh)
            #pragma unroll
            for (int nf = 0; nf < 4; ++nf)
                #pragma unroll
                for (int r = 0; r < 4; ++r)
                    red[qg][(qh * 16 + nf * 4 + r) * 64 + lane] = acc[qh][nf][r];
    }
    __syncthreads();
    if (kh == 0) {
        #pragma unroll
        for (int qh = 0; qh < 4; ++qh)
            #pragma unroll
            for (int nf = 0; nf < 4; ++nf)
                #pragma unroll
                for (int r = 0; r < 4; ++r)
                    acc[qh][nf][r] += red[qg][(qh * 16 + nf * 4 + r) * 64 + lane];

        // epilogue: C/D col=lane&15 (n), row=lg*4+r (q)
        #pragma unroll
        for (int qh = 0; qh < 4; ++qh)
            #pragma unroll
            for (int nf = 0; nf < 4; ++nf)
                #pragma unroll
                for (int r = 0; r < 4; ++r)
                    out[(size_t)(qb + qh * 16 + lg * 4 + r) * SOUT + nf * 16 + l15] =
                        acc[qh][nf][r];
    }
}

// ---------------- fallback (round-1 kernel) if d_ws too small ----------------
__launch_bounds__(256)
__global__ void rbf_tps_fallback(const float* __restrict__ x,
                                 const float* __restrict__ y,
                                 const float* __restrict__ coeffs,
                                 const float* __restrict__ shift,
                                 const float* __restrict__ scale,
                                 float* __restrict__ out) {
    __shared__ float4 ytile[NC];
    const int tid = threadIdx.x;
    for (int j = tid; j < NC; j += 256) {
        const float a = y[j * 3], b = y[j * 3 + 1], c = y[j * 3 + 2];
        ytile[j] = make_float4(a, b, c, a * a + b * b + c * c);
    }
    __syncthreads();
    const int q = blockIdx.x * 256 + tid;
    const float x0 = x[q * 3], x1 = x[q * 3 + 1], x2 = x[q * 3 + 2];
    const float xsq = x0 * x0 + x1 * x1 + x2 * x2;
    const float xh0 = (x0 - shift[0]) / scale[0];
    const float xh1 = (x1 - shift[1]) / scale[1];
    const float xh2 = (x2 - shift[2]) / scale[2];
    float acc[SOUT];
    {
        const float* c0 = &coeffs[(size_t)(NC + 0) * SOUT];
        const float* c1 = &coeffs[(size_t)(NC + 1) * SOUT];
        const float* c2 = &coeffs[(size_t)(NC + 2) * SOUT];
        const float* c3 = &coeffs[(size_t)(NC + 3) * SOUT];
        #pragma unroll
        for (int s = 0; s < SOUT; ++s)
            acc[s] = c0[s] + xh0 * c1[s] + xh1 * c2[s] + xh2 * c3[s];
    }
    #pragma unroll 2
    for (int j = 0; j < NC; ++j) {
        const float4 yj = ytile[j];
        const float dot = x0 * yj.x + x1 * yj.y + x2 * yj.z;
        float r2 = fmaf(-2.0f, dot, xsq + yj.w);
        r2 = fmaxf(r2, 0.0f);
        const float f = 0.5f * r2 * __logf(fmaxf(r2, 1e-37f));
        const float* __restrict__ cj = &coeffs[(size_t)j * SOUT];
        #pragma unroll
        for (int s = 0; s < SOUT; ++s) acc[s] = fmaf(f, cj[s], acc[s]);
    }
    float4* o4 = (float4*)&out[(size_t)q * SOUT];
    #pragma unroll
    for (int s = 0; s < SOUT / 4; ++s)
        o4[s] = make_float4(acc[4 * s], acc[4 * s + 1], acc[4 * s + 2], acc[4 * s + 3]);
}

extern "C" void kernel_launch(void* const* d_in, const int* in_sizes, int n_in,
                              void* d_out, int out_size, void* d_ws, size_t ws_size,
                              hipStream_t stream) {
    const float* x      = (const float*)d_in[0];
    const float* y      = (const float*)d_in[1];
    const float* coeffs = (const float*)d_in[2];
    const float* shift  = (const float*)d_in[3];
    const float* scale  = (const float*)d_in[4];
    float* out = (float*)d_out;

    const size_t bp_bytes = (size_t)65 * 4 * 2 * 64 * 8 * sizeof(_Float16); // 532,480
    const size_t ye_bytes = (size_t)KTOT * 8 * sizeof(_Float16);            //  66,560

    if (ws_size >= bp_bytes + ye_bytes) {
        _Float16* bpw = (_Float16*)d_ws;
        _Float16* yep = (_Float16*)((char*)d_ws + bp_bytes);
        hipLaunchKernelGGL(prep_bpack, dim3((65 * 4 * 2 * 64 + 255) / 256), dim3(256),
                           0, stream, coeffs, bpw);
        hipLaunchKernelGGL(prep_ye, dim3((KTOT + 255) / 256), dim3(256),
                           0, stream, y, yep);
        hipLaunchKernelGGL(rbf_mfma16, dim3(NQ / BM), dim3(256), 0, stream,
                           x, yep, shift, scale, bpw, out);
    } else {
        hipLaunchKernelGGL(rbf_tps_fallback, dim3(NQ / 256), dim3(256),
                           0, stream, x, y, coeffs, shift, scale, out);
    }
}

// Round 20
// 67.284 us; speedup vs baseline: 1.0621x; 1.0375x over previous
//
#include <hip/hip_runtime.h>

#define NQ   65536
#define NC   4096
#define SOUT 64
#define NR   4                 // monomials (DEGREE=1, NDIM=3)
#define KTOT (NC + 64)         // 4160: k padded (chunk 64 = poly frags)
#define BM   64                // 2 q-groups x 32 q-rows per block
#define NCH  (NC / 64)         // 64 r2 chunks of BK=64
#define BP_BLOCKS 130          // prep: 130 blocks cover 33280 bpack items
#define YE_BLOCKS 17           // prep: 17 blocks cover 4160 ye rows

typedef float    f32x4 __attribute__((ext_vector_type(4)));
typedef _Float16 f16x8 __attribute__((ext_vector_type(8)));
typedef __fp16   h16x2 __attribute__((ext_vector_type(2)));
typedef unsigned uint4v __attribute__((ext_vector_type(4)));

// ---------------- single fused pre-kernel (writes d_ws; deterministic) -------
// blockIdx.x < BP_BLOCKS: packed-B table; else: ye table (+0.02 ysq bias).
// Both halves index-identical to the round-16-verified pair of kernels.
__global__ void prep_all(const float* __restrict__ coeffs,
                         const float* __restrict__ y,
                         _Float16* __restrict__ bp,
                         _Float16* __restrict__ ye) {
    if (blockIdx.x < BP_BLOCKS) {
        const int idx = blockIdx.x * 256 + threadIdx.x;
        if (idx >= 65 * 4 * 2 * 64) return;
        const int l  = idx & 63;
        const int kk = (idx >> 6) & 1;
        const int nf = (idx >> 7) & 3;
        const int ch = idx >> 9;
        const int n  = nf * 16 + (l & 15);
        const int ks = ch * 64 + kk * 32 + (l >> 4) * 8;
        f16x8 v;
        #pragma unroll
        for (int j = 0; j < 8; ++j) {
            const int k = ks + j;
            float f = 0.0f;
            if (k < NC)           f = coeffs[(size_t)k * SOUT + n] * 0.34657359f;
            else if (k < NC + NR) f = coeffs[(size_t)k * SOUT + n];
            v[j] = (_Float16)f;
        }
        *(f16x8*)(bp + (size_t)idx * 8) = v;
    } else {
        const int k = (blockIdx.x - BP_BLOCKS) * 256 + threadIdx.x;
        if (k >= KTOT) return;
        f16x8 r = {};
        if (k < NC) {
            const float a = y[k * 3 + 0], b = y[k * 3 + 1], c = y[k * 3 + 2];
            r[0] = (_Float16)(-2.0f * a); r[1] = (_Float16)(-2.0f * b);
            r[2] = (_Float16)(-2.0f * c); r[3] = (_Float16)1.0f;
            r[4] = (_Float16)(a * a + b * b + c * c + 0.02f);
        }
        *(f16x8*)(ye + (size_t)k * 8) = r;
    }
}

// ---------------- main kernel ------------------------------------------------
// Round-16 structure and math EXACTLY (verified best: 63.5 us kernel, absmax
// 4.0): 2-way K-split, plain C++ loads, register A-frag trick, no clamp (ysq
// bias + free |.| modifier on v_log), scalar muls, LDS merge. Packed-f32 asm
// is retired (rounds 15/19: corrupt results under both encodings).
// Only change: running pointers yp/b0/b2 advance once per chunk so all
// intra-chunk load offsets are <=3072-byte immediates (folds into offset:N).
__launch_bounds__(256, 4)
__global__ void rbf_mfma18(const float* __restrict__ x,
                           const _Float16* __restrict__ ye,
                           const float* __restrict__ shift,
                           const float* __restrict__ scale,
                           const _Float16* __restrict__ bp,
                           float* __restrict__ out) {
    __shared__ float red[2][32 * 64];   // 16 KB: [qg][elem][lane]

    const int t    = threadIdx.x;
    const int wave = t >> 6;
    const int lane = t & 63;
    const int l15  = lane & 15;
    const int lg   = lane >> 4;
    const int qg   = wave & 1;
    const int kh   = wave >> 1;
    const int qb   = blockIdx.x * BM + qg * 32;   // this wave's 32 q-rows
    const int s    = kh * 32;                     // first chunk of this k-half

    // Xe B-fragments per q-half: lg==0 lanes hold [x0,x1,x2,xsq,1,0,0,0]
    f16x8 xef[2];
    uint2  poly01[2];
    #pragma unroll
    for (int qh = 0; qh < 2; ++qh) {
        const int q = qb + qh * 16 + l15;
        const float a = x[q * 3 + 0], b = x[q * 3 + 1], c = x[q * 3 + 2];
        f16x8 v = {};
        if (lg == 0) {
            v[0] = (_Float16)a; v[1] = (_Float16)b; v[2] = (_Float16)c;
            v[3] = (_Float16)(a * a + b * b + c * c); v[4] = (_Float16)1.0f;
        }
        xef[qh] = v;
        h16x2 p0 = __builtin_amdgcn_cvt_pkrtz(1.0f, (a - shift[0]) / scale[0]);
        h16x2 p1 = __builtin_amdgcn_cvt_pkrtz((b - shift[1]) / scale[1],
                                              (c - shift[2]) / scale[2]);
        poly01[qh].x = __builtin_bit_cast(unsigned, p0);
        poly01[qh].y = __builtin_bit_cast(unsigned, p1);
    }

    // running per-lane pointers (advance once per chunk; imm offsets inside)
    const _Float16* yp = ye + ((size_t)((l15 >> 2) * 8 + (l15 & 3))) * 8
                            + (size_t)s * 512;
    const _Float16* b0 = bp + (size_t)lane * 8 + (size_t)s * 4096;  // nf0/1
    const _Float16* b2 = b0 + 2048;                                 // nf2/3
    const _Float16* bpl = bp + (size_t)lane * 8;                    // poly tail

    f32x4 acc[2][4] = {};   // [qh][nf]

    for (int ch = 0; ch < 32; ++ch) {
        // ---- Y rows (head of the r2 chain; issue first) ----
        f16x8 Y[4];
        Y[0] = *(const f16x8*)(yp + 0);
        Y[1] = *(const f16x8*)(yp + 256);
        Y[2] = *(const f16x8*)(yp + 32);
        Y[3] = *(const f16x8*)(yp + 288);

        // ---- B fragments: coalesced 1 KB bursts, imm offsets ----
        f16x8 B[4][2];
        B[0][0] = *(const f16x8*)(b0 + 0);
        B[0][1] = *(const f16x8*)(b0 + 512);
        B[1][0] = *(const f16x8*)(b0 + 1024);
        B[1][1] = *(const f16x8*)(b0 + 1536);
        B[2][0] = *(const f16x8*)(b2 + 0);
        B[2][1] = *(const f16x8*)(b2 + 512);
        B[3][0] = *(const f16x8*)(b2 + 1024);
        B[3][1] = *(const f16x8*)(b2 + 1536);

        yp += 512; b0 += 4096; b2 += 4096;

        // ---- per q-half: r2 tiles + f-eval + out-GEMM ----
        #pragma unroll
        for (int qh = 0; qh < 2; ++qh) {
            uint2 w[4];
            #pragma unroll
            for (int kt = 0; kt < 4; ++kt) {
                f32x4 z = {};
                const f32x4 r2 = __builtin_amdgcn_mfma_f32_16x16x32_f16(
                    Y[kt], xef[qh], z, 0, 0, 0);
                float f[4];
                #pragma unroll
                for (int r = 0; r < 4; ++r) {
                    // r2 > 0 by ysq bias; |.| folds into v_log as input modifier
                    f[r] = r2[r] * __log2f(__builtin_fabsf(r2[r]));
                }
                h16x2 h0 = __builtin_amdgcn_cvt_pkrtz(f[0], f[1]);
                h16x2 h1 = __builtin_amdgcn_cvt_pkrtz(f[2], f[3]);
                w[kt].x = __builtin_bit_cast(unsigned, h0);
                w[kt].y = __builtin_bit_cast(unsigned, h1);
            }
            const uint4v a0 = {w[0].x, w[0].y, w[2].x, w[2].y};
            const uint4v a1 = {w[1].x, w[1].y, w[3].x, w[3].y};
            const f16x8 af0 = __builtin_bit_cast(f16x8, a0);
            const f16x8 af1 = __builtin_bit_cast(f16x8, a1);
            #pragma unroll
            for (int nf = 0; nf < 4; ++nf) {
                acc[qh][nf] = __builtin_amdgcn_mfma_f32_16x16x32_f16(
                    af0, B[nf][0], acc[qh][nf], 0, 0, 0);
                acc[qh][nf] = __builtin_amdgcn_mfma_f32_16x16x32_f16(
                    af1, B[nf][1], acc[qh][nf], 0, 0, 0);
            }
        }
    }

    if (kh == 1) {
        // ---- poly tail: chunk 64, kk=0 frags; A = [1,xh0,xh1,xh2,0...] ----
        #pragma unroll
        for (int qh = 0; qh < 2; ++qh) {
            uint4v ap = {};
            if (lg == 0) { ap.x = poly01[qh].x; ap.y = poly01[qh].y; }
            const f16x8 afp = __builtin_bit_cast(f16x8, ap);
            #pragma unroll
            for (int nf = 0; nf < 4; ++nf) {
                const f16x8 bpf = *(const f16x8*)(
                    bpl + ((size_t)((NCH * 4 + nf) * 2) << 9));
                acc[qh][nf] = __builtin_amdgcn_mfma_f32_16x16x32_f16(
                    afp, bpf, acc[qh][nf], 0, 0, 0);
            }
        }
        // write partials: [elem][lane] layout -> conflict-free b32 stores
        #pragma unroll
        for (int qh = 0; qh < 2; ++qh)
            #pragma unroll
            for (int nf = 0; nf < 4; ++nf)
                #pragma unroll
                for (int r = 0; r < 4; ++r)
                    red[qg][(qh * 16 + nf * 4 + r) * 64 + lane] = acc[qh][nf][r];
    }
    __syncthreads();
    if (kh == 0) {
        #pragma unroll
        for (int qh = 0; qh < 2; ++qh)
            #pragma unroll
            for (int nf = 0; nf < 4; ++nf)
                #pragma unroll
                for (int r = 0; r < 4; ++r)
                    acc[qh][nf][r] += red[qg][(qh * 16 + nf * 4 + r) * 64 + lane];

        // epilogue: C/D col=lane&15 (n), row=lg*4+r (q)
        #pragma unroll
        for (int qh = 0; qh < 2; ++qh)
            #pragma unroll
            for (int nf = 0; nf < 4; ++nf)
                #pragma unroll
                for (int r = 0; r < 4; ++r)
                    out[(size_t)(qb + qh * 16 + lg * 4 + r) * SOUT + nf * 16 + l15] =
                        acc[qh][nf][r];
    }
}

// ---------------- fallback (round-1 kernel) if d_ws too small ----------------
__launch_bounds__(256)
__global__ void rbf_tps_fallback(const float* __restrict__ x,
                                 const float* __restrict__ y,
                                 const float* __restrict__ coeffs,
                                 const float* __restrict__ shift,
                                 const float* __restrict__ scale,
                                 float* __restrict__ out) {
    __shared__ float4 ytile[NC];
    const int tid = threadIdx.x;
    for (int j = tid; j < NC; j += 256) {
        const float a = y[j * 3], b = y[j * 3 + 1], c = y[j * 3 + 2];
        ytile[j] = make_float4(a, b, c, a * a + b * b + c * c);
    }
    __syncthreads();
    const int q = blockIdx.x * 256 + tid;
    const float x0 = x[q * 3], x1 = x[q * 3 + 1], x2 = x[q * 3 + 2];
    const float xsq = x0 * x0 + x1 * x1 + x2 * x2;
    const float xh0 = (x0 - shift[0]) / scale[0];
    const float xh1 = (x1 - shift[1]) / scale[1];
    const float xh2 = (x2 - shift[2]) / scale[2];
    float acc[SOUT];
    {
        const float* c0 = &coeffs[(size_t)(NC + 0) * SOUT];
        const float* c1 = &coeffs[(size_t)(NC + 1) * SOUT];
        const float* c2 = &coeffs[(size_t)(NC + 2) * SOUT];
        const float* c3 = &coeffs[(size_t)(NC + 3) * SOUT];
        #pragma unroll
        for (int s = 0; s < SOUT; ++s)
            acc[s] = c0[s] + xh0 * c1[s] + xh1 * c2[s] + xh2 * c3[s];
    }
    #pragma unroll 2
    for (int j = 0; j < NC; ++j) {
        const float4 yj = ytile[j];
        const float dot = x0 * yj.x + x1 * yj.y + x2 * yj.z;
        float r2 = fmaf(-2.0f, dot, xsq + yj.w);
        r2 = fmaxf(r2, 0.0f);
        const float f = 0.5f * r2 * __logf(fmaxf(r2, 1e-37f));
        const float* __restrict__ cj = &coeffs[(size_t)j * SOUT];
        #pragma unroll
        for (int s = 0; s < SOUT; ++s) acc[s] = fmaf(f, cj[s], acc[s]);
    }
    float4* o4 = (float4*)&out[(size_t)q * SOUT];
    #pragma unroll
    for (int s = 0; s < SOUT / 4; ++s)
        o4[s] = make_float4(acc[4 * s], acc[4 * s + 1], acc[4 * s + 2], acc[4 * s + 3]);
}

extern "C" void kernel_launch(void* const* d_in, const int* in_sizes, int n_in,
                              void* d_out, int out_size, void* d_ws, size_t ws_size,
                              hipStream_t stream) {
    const float* x      = (const float*)d_in[0];
    const float* y      = (const float*)d_in[1];
    const float* coeffs = (const float*)d_in[2];
    const float* shift  = (const float*)d_in[3];
    const float* scale  = (const float*)d_in[4];
    float* out = (float*)d_out;

    const size_t bp_bytes = (size_t)65 * 4 * 2 * 64 * 8 * sizeof(_Float16); // 532,480
    const size_t ye_bytes = (size_t)KTOT * 8 * sizeof(_Float16);            //  66,560

    if (ws_size >= bp_bytes + ye_bytes) {
        _Float16* bpw = (_Float16*)d_ws;
        _Float16* yep = (_Float16*)((char*)d_ws + bp_bytes);
        hipLaunchKernelGGL(prep_all, dim3(BP_BLOCKS + YE_BLOCKS), dim3(256),
                           0, stream, coeffs, y, bpw, yep);
        hipLaunchKernelGGL(rbf_mfma18, dim3(NQ / BM), dim3(256), 0, stream,
                           x, yep, shift, scale, bpw, out);
    } else {
        hipLaunchKernelGGL(rbf_tps_fallback, dim3(NQ / 256), dim3(256),
                           0, stream, x, y, coeffs, shift, scale, out);
    }
}